// Round 5
// baseline (973.385 us; speedup 1.0000x reference)
//
#include <hip/hip_runtime.h>
#include <hip/hip_bf16.h>
#include <stdint.h>

// Problem constants (QKVParallelLinearWithLoRA)
#define S_TOK 16384
#define DIN   4096
#define OUTQ  4096
#define OUTKV 1024
#define NOUT  6144   // OUTQ + 2*OUTKV
#define LRANK 64

typedef __attribute__((ext_vector_type(8))) short bf16x8;           // 8 bf16 = 4 VGPR
typedef __attribute__((ext_vector_type(4))) float f32x4;            // MFMA acc frag
typedef __attribute__((ext_vector_type(4))) unsigned short u16x4;   // 4 bf16 store

static __device__ __forceinline__ unsigned short f2bf(float f) {
  uint32_t u = __float_as_uint(f);
  u += 0x7FFFu + ((u >> 16) & 1u);
  return (unsigned short)(u >> 16);
}

static __device__ __forceinline__ void gload_lds16(const void* g, void* l) {
  __builtin_amdgcn_global_load_lds((const __attribute__((address_space(1))) void*)g,
                                   (__attribute__((address_space(3))) void*)l,
                                   16, 0, 0);
}

// ---------------------------------------------------------------------------
// Kernel 1: x fp32 -> bf16
// ---------------------------------------------------------------------------
__global__ __launch_bounds__(256) void cvt_f32_bf16(const float* __restrict__ in,
                                                    unsigned short* __restrict__ out,
                                                    int n4) {
  int i = blockIdx.x * blockDim.x + threadIdx.x;
  const int stride = gridDim.x * blockDim.x;
  const float4* in4 = (const float4*)in;
  for (; i < n4; i += stride) {
    float4 v = in4[i];
    u16x4 o;
    o.x = f2bf(v.x); o.y = f2bf(v.y); o.z = f2bf(v.z); o.w = f2bf(v.w);
    *(u16x4*)(out + (size_t)i * 4) = o;
  }
}

// ---------------------------------------------------------------------------
// Kernel 2: W_eff[o][d] = W[o][d] + sum_r B_seg[o'][r] * A[seg*64+r][d] -> bf16
// ---------------------------------------------------------------------------
__global__ __launch_bounds__(256) void prep_weff(const float* __restrict__ W,
                                                 const float* __restrict__ A,
                                                 const float* __restrict__ Bq,
                                                 const float* __restrict__ Bk,
                                                 const float* __restrict__ Bv,
                                                 unsigned short* __restrict__ Weff) {
  __shared__ float As_[64][128];
  __shared__ float Bs_[64][64];
  const int o0 = blockIdx.x * 64;
  const int d0 = blockIdx.y * 128;
  const int t = threadIdx.x;

  const float* Bseg; int seg, ob;
  if (o0 < OUTQ)              { seg = 0; Bseg = Bq; ob = o0; }
  else if (o0 < OUTQ + OUTKV) { seg = 1; Bseg = Bk; ob = o0 - OUTQ; }
  else                        { seg = 2; Bseg = Bv; ob = o0 - OUTQ - OUTKV; }

  {
    const float4* src = (const float4*)(Bseg + (size_t)ob * LRANK);
    float4* dst = (float4*)&Bs_[0][0];
    for (int i = t; i < 64 * 64 / 4; i += 256) dst[i] = src[i];
  }
  for (int i = t; i < 64 * 32; i += 256) {
    int r = i >> 5, c4 = i & 31;
    *(float4*)&As_[r][c4 * 4] =
        *(const float4*)(A + (size_t)(seg * 64 + r) * DIN + d0 + c4 * 4);
  }
  __syncthreads();

  const int tx = t & 31;
  const int tg = t >> 5;
  for (int oi = tg * 8; oi < tg * 8 + 8; ++oi) {
    const int o = o0 + oi;
    float4 acc = *(const float4*)(W + (size_t)o * DIN + d0 + tx * 4);
#pragma unroll 8
    for (int r = 0; r < 64; ++r) {
      const float b = Bs_[oi][r];
      const float4 a = *(const float4*)&As_[r][tx * 4];
      acc.x += b * a.x; acc.y += b * a.y; acc.z += b * a.z; acc.w += b * a.w;
    }
    u16x4 ov;
    ov.x = f2bf(acc.x); ov.y = f2bf(acc.y); ov.z = f2bf(acc.z); ov.w = f2bf(acc.w);
    *(u16x4*)(Weff + (size_t)o * DIN + d0 + tx * 4) = ov;
  }
}

// ---------------------------------------------------------------------------
// Kernel 3: 256x256 GEMM, BK=64, 8-phase REGISTER-PREFETCHED schedule.
//   C[m,n] = sum_k Xb[m,k]*Wb[n,k] + bias[n]
// Change vs R4 (which measured: 1266 cyc/phase = 621 MFMA + 576 LDS-read,
// serialized by the in-phase read->lgkmcnt(0)->MFMA chain): each phase now
// issues the ds_reads for phase p+1 into the ALTERNATE register bank, then
// runs phase p's MFMA on the bank read last phase -- LDS read servicing
// overlaps the MFMA window. Counted lgkmcnt(N) per phase (N = reads just
// issued) + sched_barrier(0) (rule #18). ONE barrier per phase. vmcnt ledger:
// vmcnt(2) at P1/P3/P5/P7 ends guarantees each half-tile lands one phase
// before its first read-issue; staged region is never the in-flight-read
// region (verified per-phase); WAR separated by >=2 barriers. Peeled last
// group drains 2->0. Swizzle/staging/epilogue identical to R4 (0 conflicts,
// FETCH 0.59GB).
// ---------------------------------------------------------------------------
__global__ __launch_bounds__(512, 1) void gemm_bt_bias(const unsigned short* __restrict__ Xb,
                                                       const unsigned short* __restrict__ Wb,
                                                       const float* __restrict__ bias,
                                                       float* __restrict__ C) {
  __shared__ unsigned short Alds[32768];  // 4 regions x 16KB: R(buf,ks)=(buf*2+ks)
  __shared__ unsigned short Blds[32768];

  // 2-D co-residency swizzle: XCD x owns mt-band [8x,8x+8); 32 concurrent
  // slots tile 8mt x 4nt; generations sweep nt. (R4: FETCH 3.2x lower)
  const int bid = blockIdx.x;
  const int x = bid & 7;
  const int l = bid >> 3;
  const int g = l >> 5;
  const int i5 = l & 31;
  const int mt = x * 8 + (i5 & 7);
  const int nt = g * 4 + (i5 >> 3);
  const int m0 = mt * 256;
  const int n0 = nt * 256;

  const int t = threadIdx.x;
  const int lane = t & 63;
  const int w = t >> 6;
  const int wm = (w >> 2) * 128;          // 2 waves in M
  const int wn = (w & 3) * 64;            // 4 waves in N

  // staging: thread t -> region row t>>2 (+128 second gload), phys slot t&3;
  // logical k-slot = (t&3)^((trow>>1)&3) (inverse swizzle on global source).
  const int trow = t >> 2;
  const int ksl = (t & 3) ^ ((trow >> 1) & 3);
  const size_t gA0 = (size_t)(m0 + trow) * DIN + ksl * 8;
  const size_t gA1 = (size_t)(m0 + 128 + trow) * DIN + ksl * 8;
  const size_t gB0 = (size_t)(n0 + trow) * DIN + ksl * 8;
  const size_t gB1 = (size_t)(n0 + 128 + trow) * DIN + ksl * 8;
  const int ldst = t * 8;

#define STAGE_A(T, kh) do {                                                   \
    const int rb_ = (((T) & 1) * 2 + (kh)) * 8192;                            \
    const size_t ko_ = (size_t)((T) * 64 + (kh) * 32);                        \
    gload_lds16(Xb + gA0 + ko_, &Alds[rb_ + ldst]);                           \
    gload_lds16(Xb + gA1 + ko_, &Alds[rb_ + 4096 + ldst]);                    \
  } while (0)
#define STAGE_B(T, kh) do {                                                   \
    const int rb_ = (((T) & 1) * 2 + (kh)) * 8192;                            \
    const size_t ko_ = (size_t)((T) * 64 + (kh) * 32);                        \
    gload_lds16(Wb + gB0 + ko_, &Blds[rb_ + ldst]);                           \
    gload_lds16(Wb + gB1 + ko_, &Blds[rb_ + 4096 + ldst]);                    \
  } while (0)

  // fragment read offsets (bytes within 16KB region)
  const int lr = lane & 15;
  const int ks16 = (lane >> 4) * 16;
  const int fxor = ((lr >> 1) & 3) << 4;
  const int aoff = ((wm + lr) * 64 + ks16) ^ fxor;
  const int boff = ((wn + lr) * 64 + ks16) ^ fxor;

  f32x4 acc[8][4];
#pragma unroll
  for (int i = 0; i < 8; ++i)
#pragma unroll
    for (int j = 0; j < 4; ++j)
      acc[i][j] = f32x4{0.f, 0.f, 0.f, 0.f};

  bf16x8 af0[4], af1[4], bq0[4], bq1[4];  // double-banked frag registers

  // rbyte: region byte offset. fh selects A-frag row half (mi 0..3 / 4..7).
#define RD_A(bank, rbyte, fh) do {                                            \
    const char* Ar_ = (const char*)Alds + (rbyte);                            \
    _Pragma("unroll")                                                         \
    for (int j_ = 0; j_ < 4; ++j_)                                            \
      bank[j_] = *(const bf16x8*)(Ar_ + aoff + ((fh) * 4 + j_) * 1024);       \
  } while (0)
#define RD_B(bank, rbyte) do {                                                \
    const char* Br_ = (const char*)Blds + (rbyte);                            \
    _Pragma("unroll")                                                         \
    for (int n_ = 0; n_ < 4; ++n_)                                            \
      bank[n_] = *(const bf16x8*)(Br_ + boff + n_ * 1024);                    \
  } while (0)
#define MM(afb, bqb, fh) do {                                                 \
    __builtin_amdgcn_s_setprio(1);                                            \
    _Pragma("unroll")                                                         \
    for (int j_ = 0; j_ < 4; ++j_)                                            \
      _Pragma("unroll")                                                       \
      for (int n_ = 0; n_ < 4; ++n_)                                          \
        acc[(fh) * 4 + j_][n_] = __builtin_amdgcn_mfma_f32_16x16x32_bf16(     \
            afb[j_], bqb[n_], acc[(fh) * 4 + j_][n_], 0, 0, 0);               \
    __builtin_amdgcn_s_setprio(0);                                            \
  } while (0)
  // counted lgkm wait: waits for LAST phase's reads (this phase's N remain);
  // sched_barrier(0) stops MFMA hoisting above the wait (rule #18).
#define WTL(n) do { asm volatile("s_waitcnt lgkmcnt(" #n ")" ::: "memory");   \
    __builtin_amdgcn_sched_barrier(0); } while (0)
#define WV2() asm volatile("s_waitcnt vmcnt(2)" ::: "memory")
#define WV0() asm volatile("s_waitcnt vmcnt(0)" ::: "memory")
#define BAR() __builtin_amdgcn_s_barrier()

  // ---- prologue: stage tile 0; (0,ks0) landed -> prefetch P1's frags.
  STAGE_A(0, 0); STAGE_B(0, 0); STAGE_A(0, 1); STAGE_B(0, 1);
  asm volatile("s_waitcnt vmcnt(4)" ::: "memory");
  BAR();
  RD_A(af0, 0, 0); RD_B(bq0, 0);          // 8 reads for P1

  // ---- main loop: group computes tiles Ta=2i (buf0), Tb=2i+1 (buf1);
  // stages Tb (P1-P4) and Tc=2i+2 (P5-P8). Ledger: outstanding at P1-start
  // = {A(Ta,1),B(Ta,1)} (4); vmcnt(2) at P1/P3/P5/P7.
  for (int i = 0; i < 31; ++i) {
    const int Tb = 2 * i + 1, Tc = 2 * i + 2;
    // P1: Ta s(ks0,fh0)
    RD_A(af1, 0, 1);        STAGE_A(Tb, 0); WTL(4); MM(af0, bq0, 0); WV2(); BAR();
    // P2: Ta s(ks0,fh1)
    RD_A(af0, 16384, 0); RD_B(bq1, 16384); STAGE_B(Tb, 0); WTL(8); MM(af1, bq0, 1); BAR();
    // P3: Ta s(ks1,fh0)
    RD_A(af1, 16384, 1);    STAGE_A(Tb, 1); WTL(4); MM(af0, bq1, 0); WV2(); BAR();
    // P4: Ta s(ks1,fh1)
    RD_A(af0, 32768, 0); RD_B(bq0, 32768); STAGE_B(Tb, 1); WTL(8); MM(af1, bq1, 1); BAR();
    // P5: Tb s(ks0,fh0)
    RD_A(af1, 32768, 1);    STAGE_A(Tc, 0); WTL(4); MM(af0, bq0, 0); WV2(); BAR();
    // P6: Tb s(ks0,fh1)
    RD_A(af0, 49152, 0); RD_B(bq1, 49152); STAGE_B(Tc, 0); WTL(8); MM(af1, bq0, 1); BAR();
    // P7: Tb s(ks1,fh0)
    RD_A(af1, 49152, 1);    STAGE_A(Tc, 1); WTL(4); MM(af0, bq1, 0); WV2(); BAR();
    // P8: Tb s(ks1,fh1); prefetch next group's P1 frags from R(0,ks0)
    RD_A(af0, 0, 0); RD_B(bq0, 0);         STAGE_B(Tc, 1); WTL(8); MM(af1, bq1, 1); BAR();
  }

  // ---- peeled final group: Ta=62 (buf0), Tb=63 (buf1); stage only 63.
  RD_A(af1, 0, 1);        STAGE_A(63, 0); WTL(4); MM(af0, bq0, 0); WV2(); BAR();
  RD_A(af0, 16384, 0); RD_B(bq1, 16384); STAGE_B(63, 0); WTL(8); MM(af1, bq0, 1); BAR();
  RD_A(af1, 16384, 1);    STAGE_A(63, 1); WTL(4); MM(af0, bq1, 0); WV2(); BAR();
  RD_A(af0, 32768, 0); RD_B(bq0, 32768); STAGE_B(63, 1); WTL(8); MM(af1, bq1, 1); BAR();
  RD_A(af1, 32768, 1);                    WTL(4); MM(af0, bq0, 0); WV0(); BAR();
  RD_A(af0, 49152, 0); RD_B(bq1, 49152);  WTL(8); MM(af1, bq0, 1); BAR();
  RD_A(af1, 49152, 1);                    WTL(4); MM(af0, bq1, 0); BAR();
                                          WTL(0); MM(af1, bq1, 1);

#undef RD_A
#undef RD_B
#undef MM
#undef WTL
#undef WV2
#undef WV0
#undef BAR
#undef STAGE_A
#undef STAGE_B

  // epilogue: C/D layout col=lane&15, row=(lane>>4)*4+reg (m89/m91-verified)
  const int cr4 = (lane >> 4) * 4;
#pragma unroll
  for (int ni = 0; ni < 4; ++ni) {
    const int col = n0 + wn + ni * 16 + lr;
    const float bv = bias[col];
#pragma unroll
    for (int mi = 0; mi < 8; ++mi) {
      const int row = m0 + wm + mi * 16 + cr4;
#pragma unroll
      for (int jj = 0; jj < 4; ++jj)
        C[(size_t)(row + jj) * NOUT + col] = acc[mi][ni][jj] + bv;
    }
  }
}

// ---------------------------------------------------------------------------
extern "C" void kernel_launch(void* const* d_in, const int* in_sizes, int n_in,
                              void* d_out, int out_size, void* d_ws, size_t ws_size,
                              hipStream_t stream) {
  const float* x    = (const float*)d_in[0];
  const float* Wqkv = (const float*)d_in[1];
  const float* bias = (const float*)d_in[2];
  const float* Aq   = (const float*)d_in[3];
  const float* Bq   = (const float*)d_in[4];
  const float* Bk   = (const float*)d_in[5];
  const float* Bv   = (const float*)d_in[6];
  float* out = (float*)d_out;

  unsigned short* xb = (unsigned short*)d_ws;                 // 128 MB
  unsigned short* wb = xb + (size_t)S_TOK * DIN;              // 48 MB

  cvt_f32_bf16<<<2048, 256, 0, stream>>>(x, xb, S_TOK * DIN / 4);

  dim3 g1(NOUT / 64, DIN / 128);
  prep_weff<<<g1, 256, 0, stream>>>(Wqkv, Aq, Bq, Bk, Bv, wb);

  gemm_bt_bias<<<1536, 512, 0, stream>>>(xb, wb, bias, out);
}